// Round 8
// baseline (475.035 us; speedup 1.0000x reference)
//
#include <hip/hip_runtime.h>
#include <hip/hip_bf16.h>

typedef __bf16 bf16;
typedef __bf16 bf16x8 __attribute__((ext_vector_type(8)));
typedef float  f32x4  __attribute__((ext_vector_type(4)));

#define MFMA16(A,B,C) __builtin_amdgcn_mfma_f32_16x16x32_bf16((A),(B),(C),0,0,0)

constexpr float SCALE = 0.17677669529663687f;   // 32^-0.5

// ---- ws layout (bytes) ----
constexpr size_t CB_OFF    = 0;                        // f32 [64 w][8 h][64 m][64 j] = 8 MB
constexpr size_t QKVW_OFF  = 8388608;                  // bf16 [768][256]
constexpr size_t PROJW_OFF = QKVW_OFF + 768*256*2;     // bf16 [256][256]
constexpr size_t QI_OFF    = PROJW_OFF + 256*256*2;    // 8,912,896 (256B aligned)
constexpr size_t TEN_ELEMS = 51380224ull;              // 4096*8*49*32 (bf16 elems)
constexpr size_t AO_OFF    = QI_OFF + 3*TEN_ELEMS*2;   // bf16 [200704][256]

__global__ __launch_bounds__(256) void build_cb_kernel(
    const float* __restrict__ bias_table, const float* __restrict__ mask,
    const int* __restrict__ rel_index, float* __restrict__ cb) {
  int idx = blockIdx.x * 256 + threadIdx.x;            // [64 w][8 h][64 m][64 j]
  int j = idx & 63, m = (idx >> 6) & 63, h = (idx >> 12) & 7, w = idx >> 15;
  float v = 0.f;
  if (j < 49 && m < 49)
    v = bias_table[rel_index[m * 49 + j] * 8 + h] + mask[(w * 49 + m) * 49 + j];
  cb[idx] = v;
}

__global__ __launch_bounds__(256) void cvt_w_kernel(
    const float* __restrict__ qkv_w, const float* __restrict__ proj_w,
    bf16* __restrict__ qkv_wb, bf16* __restrict__ proj_wb) {
  int i = blockIdx.x * 256 + threadIdx.x;              // 262,144 total
  if (i < 768 * 256) qkv_wb[i] = (bf16)qkv_w[i];
  else               proj_wb[i - 768 * 256] = (bf16)proj_w[i - 768 * 256];
}

// swizzled LDS tile helper: [row][64 k], 8-elem chunks XOR'd by row&7
__device__ __forceinline__ bf16x8 frag(const bf16* S, int row, int kchunk) {
  return *reinterpret_cast<const bf16x8*>(&S[row * 64 + ((kchunk ^ (row & 7)) * 8)]);
}

// ---------------------------------------------------------------------------
// GEMM A v2: qkv = x @ qkv_w^T (+bias, Q pre-scaled), scatter to q/k/v tiles.
// BM=64, BN=768 (full), BK=64. 512 thr / 8 waves; wave wv owns n in
// [96wv, 96wv+96). x staged+converted ONCE per row; B-frags direct from L2.
// T14 split: next-slice x loads issued before the MFMA phase.
// grid 3136 = 8 XCD chunks x 392.
// ---------------------------------------------------------------------------
__global__ __launch_bounds__(512, 2) void gemm_qkv_kernel(
    const float* __restrict__ x, const bf16* __restrict__ qkv_wb,
    const float* __restrict__ qkv_b, bf16* __restrict__ qkv_i) {
  __shared__ __align__(16) bf16 As[64 * 64];
  const int bid = blockIdx.x;
  const int xcd = bid & 7, idx = bid >> 3;             // 3136 = 8 * 392
  const int m_t = xcd * 392 + idx;
  const int tid = threadIdx.x;
  const int wv = tid >> 6, l = tid & 63, l15 = l & 15, lgp = l >> 4;

  // staging geometry: 512 chunks of 8 elems = 64 rows x 8 kchunks, 1/thread
  const int srow = tid >> 3, skc = tid & 7;
  const float* sg = x + (size_t)(m_t * 64 + srow) * 256 + skc * 8;

  const f32x4 fzero = {0.f, 0.f, 0.f, 0.f};
  f32x4 acc[4][6];
#pragma unroll
  for (int mt = 0; mt < 4; ++mt)
#pragma unroll
    for (int nt = 0; nt < 6; ++nt) acc[mt][nt] = fzero;

  f32x4 s0 = *reinterpret_cast<const f32x4*>(sg);
  f32x4 s1 = *reinterpret_cast<const f32x4*>(sg + 4);

#pragma unroll
  for (int ks = 0; ks < 4; ++ks) {
    // convert staged regs -> LDS (swizzled)
    {
      bf16x8 v8;
#pragma unroll
      for (int e = 0; e < 4; ++e) { v8[e] = (bf16)s0[e]; v8[e + 4] = (bf16)s1[e]; }
      *reinterpret_cast<bf16x8*>(&As[srow * 64 + ((skc ^ (srow & 7)) * 8)]) = v8;
    }
    __syncthreads();
    if (ks < 3) {                                      // early-issue next slice
      s0 = *reinterpret_cast<const f32x4*>(sg + (ks + 1) * 64);
      s1 = *reinterpret_cast<const f32x4*>(sg + (ks + 1) * 64 + 4);
    }
#pragma unroll
    for (int kk = 0; kk < 2; ++kk) {
      bf16x8 Af[4], Bf[6];
#pragma unroll
      for (int mt = 0; mt < 4; ++mt) Af[mt] = frag(As, mt * 16 + l15, kk * 4 + lgp);
#pragma unroll
      for (int nt = 0; nt < 6; ++nt) {
        int n_row = wv * 96 + nt * 16 + l15;
        Bf[nt] = *reinterpret_cast<const bf16x8*>(
            qkv_wb + (size_t)n_row * 256 + ks * 64 + kk * 32 + lgp * 8);
      }
#pragma unroll
      for (int mt = 0; mt < 4; ++mt)
#pragma unroll
        for (int nt = 0; nt < 6; ++nt) acc[mt][nt] = MFMA16(Af[mt], Bf[nt], acc[mt][nt]);
    }
    __syncthreads();
  }

  // epilogue: scatter to q/k/v [b][h][49][32] with bias (+SCALE for q)
  float bias[6]; int hh[6], dd[6], ts[6];
#pragma unroll
  for (int nt = 0; nt < 6; ++nt) {
    int n_g = wv * 96 + nt * 16 + l15;
    bias[nt] = qkv_b[n_g];
    ts[nt] = n_g >> 8;                                 // 0:q 1:k 2:v
    int nl = n_g & 255;
    hh[nt] = nl >> 5; dd[nt] = nl & 31;
  }
#pragma unroll
  for (int mt = 0; mt < 4; ++mt) {
#pragma unroll
    for (int r = 0; r < 4; ++r) {
      int r_g = m_t * 64 + mt * 16 + lgp * 4 + r;
      int b = r_g / 49, m = r_g - b * 49;
#pragma unroll
      for (int nt = 0; nt < 6; ++nt) {
        float sc = (ts[nt] == 0) ? SCALE : 1.0f;
        qkv_i[(size_t)ts[nt] * TEN_ELEMS +
              ((size_t)(b * 8 + hh[nt]) * 49 + m) * 32 + dd[nt]] =
            (bf16)((acc[mt][nt][r] + bias[nt]) * sc);
      }
    }
  }
}

// ---------------------------------------------------------------------------
// D-frag pair (16x16 tiles Ta=rows 0-15, Tb=rows 16-31 along p) -> A/B frag
// over k=p. Validated R5/R6 audit. Output lane(l15,lgp) reg u: p = lgp*8+u.
// ---------------------------------------------------------------------------
__device__ __forceinline__ bf16x8 repack8(f32x4 Ta, f32x4 Tb, int l15, int lgp) {
  const int s0 = l15 + ((lgp & 1) << 5);
  const bool hi = (lgp & 2) != 0;
  bf16x8 F;
#pragma unroll
  for (int r = 0; r < 4; ++r) {
    float a0 = __shfl(Ta[r], s0);
    float b0 = __shfl(Tb[r], s0);
    F[r] = (bf16)(hi ? b0 : a0);
    float a1 = __shfl(Ta[r], s0 + 16);
    float b1 = __shfl(Tb[r], s0 + 16);
    F[r + 4] = (bf16)(hi ? b1 : a1);
  }
  return F;
}

// ---------------------------------------------------------------------------
// attn: one wave per (window b, head h). S^T = K.Q -> register softmax ->
// PV -> ao[b*49+m][256]. grid 8192 x 256 thr (4 waves).
// ---------------------------------------------------------------------------
__global__ __launch_bounds__(256) void attn_kernel(
    const bf16* __restrict__ qkv_i, const float* __restrict__ cb,
    bf16* __restrict__ ao) {
  __shared__ __align__(16) bf16 Vs[4][64 * 32];
  const int tid = threadIdx.x, wv = tid >> 6, l = tid & 63;
  const int l15 = l & 15, lgp = l >> 4;
  const int g = blockIdx.x * 4 + wv;
  const int b = g >> 3, h = g & 7;

  const bf16* qp = qkv_i + (size_t)(b * 8 + h) * 1568;          // 49*32
  const bf16* kp = qp + TEN_ELEMS;
  const bf16* vp = kp + TEN_ELEMS;
  bf16* vsm = &Vs[wv][0];

  // stage V rows 0..48: 1568 elems = 196 chunks of 8
#pragma unroll
  for (int i = 0; i < 4; ++i) {
    int c = i * 64 + l;
    if (c < 196)
      *reinterpret_cast<bf16x8*>(&vsm[c * 8]) =
          *reinterpret_cast<const bf16x8*>(vp + c * 8);
  }
  // zero rows 49..63: 480 elems = 60 chunks of 8
  {
    const bf16x8 z8 = {(bf16)0.f,(bf16)0.f,(bf16)0.f,(bf16)0.f,
                       (bf16)0.f,(bf16)0.f,(bf16)0.f,(bf16)0.f};
    if (l < 60) *reinterpret_cast<bf16x8*>(&vsm[1568 + l * 8]) = z8;
  }
  __syncthreads();

  bf16x8 Qf[4], Kf[4];
#pragma unroll
  for (int mt = 0; mt < 4; ++mt) {
    int m = mt * 16 + l15; int mc = m < 49 ? m : 48;
    Qf[mt] = *reinterpret_cast<const bf16x8*>(qp + mc * 32 + lgp * 8);
  }
#pragma unroll
  for (int jt = 0; jt < 4; ++jt) {
    int j = jt * 16 + l15; int jc = j < 49 ? j : 48;
    Kf[jt] = *reinterpret_cast<const bf16x8*>(kp + jc * 32 + lgp * 8);
  }
  // V B-frags: lane l15 = col d, k = j (per-elem LDS gather)
  bf16x8 Vb[2][2];
#pragma unroll
  for (int dt = 0; dt < 2; ++dt)
#pragma unroll
    for (int ksx = 0; ksx < 2; ++ksx) {
#pragma unroll
      for (int u = 0; u < 8; ++u) {
        int j = ksx * 32 + lgp * 8 + u;
        Vb[dt][ksx][u] = vsm[j * 32 + dt * 16 + l15];
      }
    }

  const float* cbp = cb + (size_t)((b & 63) * 8 + h) * 4096;
  bf16* aob = ao + (size_t)b * 12544;                  // 49*256
  const f32x4 fzero = {0.f, 0.f, 0.f, 0.f};

#pragma unroll
  for (int mt = 0; mt < 4; ++mt) {
    int mrow = mt * 16 + l15;
    f32x4 e4[4];
#pragma unroll
    for (int jt = 0; jt < 4; ++jt) e4[jt] = MFMA16(Kf[jt], Qf[mt], fzero);
#pragma unroll
    for (int jt = 0; jt < 4; ++jt) {
      f32x4 c4 = *reinterpret_cast<const f32x4*>(cbp + mrow * 64 + jt * 16 + lgp * 4);
#pragma unroll
      for (int r = 0; r < 4; ++r) e4[jt][r] += c4[r];
    }
    // kill pad keys j>=49 (jt==3: j = 48 + lgp*4 + r, keep only j==48)
    if (lgp != 0) { e4[3][0] = -3.0e38f; }
    e4[3][1] = -3.0e38f; e4[3][2] = -3.0e38f; e4[3][3] = -3.0e38f;

    float mx = e4[0][0];
#pragma unroll
    for (int jt = 0; jt < 4; ++jt)
#pragma unroll
      for (int r = 0; r < 4; ++r) mx = fmaxf(mx, e4[jt][r]);
    mx = fmaxf(mx, __shfl_xor(mx, 16));
    mx = fmaxf(mx, __shfl_xor(mx, 32));
    float sum = 0.f;
#pragma unroll
    for (int jt = 0; jt < 4; ++jt)
#pragma unroll
      for (int r = 0; r < 4; ++r) {
        float ex = __expf(e4[jt][r] - mx);
        e4[jt][r] = ex;
        sum += ex;
      }
    sum += __shfl_xor(sum, 16);
    sum += __shfl_xor(sum, 32);
    float rinv = 1.0f / sum;
#pragma unroll
    for (int jt = 0; jt < 4; ++jt)
#pragma unroll
      for (int r = 0; r < 4; ++r) e4[jt][r] *= rinv;   // normalized P

    bf16x8 Pf0 = repack8(e4[0], e4[1], l15, lgp);      // k = j in [0,32)
    bf16x8 Pf1 = repack8(e4[2], e4[3], l15, lgp);      // k = j in [32,64)
    f32x4 pv[2];
#pragma unroll
    for (int dt = 0; dt < 2; ++dt) {
      pv[dt] = MFMA16(Pf0, Vb[dt][0], fzero);
      pv[dt] = MFMA16(Pf1, Vb[dt][1], pv[dt]);
    }
    // D: col l15 = d, row = m = mt*16 + lgp*4 + r
#pragma unroll
    for (int r = 0; r < 4; ++r) {
      int m_g = mt * 16 + lgp * 4 + r;
      if (m_g < 49) {
#pragma unroll
        for (int dt = 0; dt < 2; ++dt)
          aob[m_g * 256 + h * 32 + dt * 16 + l15] = (bf16)pv[dt][r];
      }
    }
  }
}

// ---------------------------------------------------------------------------
// GEMM C: out = ao @ proj_w^T + proj_b  (dense f32 output)
// ---------------------------------------------------------------------------
__global__ __launch_bounds__(256) void gemm_proj_kernel(
    const bf16* __restrict__ ao, const bf16* __restrict__ proj_wb,
    const float* __restrict__ proj_b, float* __restrict__ out) {
  __shared__ __align__(16) bf16 As[128 * 64];
  __shared__ __align__(16) bf16 Bs[128 * 64];
  const int bid = blockIdx.x;                          // 3136 = 8 * 392
  const int xcd = bid & 7, idx = bid >> 3;
  const int m_t = xcd * 196 + idx / 2;
  const int n_t = idx % 2;
  const int tid = threadIdx.x;
  const int wv = tid >> 6, l = tid & 63, l15 = l & 15, lgp = l >> 4;
  const int wr = wv >> 1, wc = wv & 1;

  const f32x4 fzero = {0.f, 0.f, 0.f, 0.f};
  f32x4 acc[4][4];
#pragma unroll
  for (int mt = 0; mt < 4; ++mt)
#pragma unroll
    for (int nt = 0; nt < 4; ++nt) acc[mt][nt] = fzero;

  for (int ks = 0; ks < 4; ++ks) {
    const int k0 = ks * 64;
#pragma unroll
    for (int i = 0; i < 4; ++i) {
      int c = i * 256 + tid;
      int row = c >> 3, kc = c & 7;
      bf16x8 a8 = *reinterpret_cast<const bf16x8*>(
          ao + (size_t)(m_t * 128 + row) * 256 + k0 + kc * 8);
      *reinterpret_cast<bf16x8*>(&As[row * 64 + ((kc ^ (row & 7)) * 8)]) = a8;
      bf16x8 w8 = *reinterpret_cast<const bf16x8*>(
          proj_wb + (size_t)(n_t * 128 + row) * 256 + k0 + kc * 8);
      *reinterpret_cast<bf16x8*>(&Bs[row * 64 + ((kc ^ (row & 7)) * 8)]) = w8;
    }
    __syncthreads();
#pragma unroll
    for (int kk = 0; kk < 2; ++kk) {
      bf16x8 Af[4], Bf[4];
#pragma unroll
      for (int mt = 0; mt < 4; ++mt) Af[mt] = frag(As, wr * 64 + mt * 16 + l15, kk * 4 + lgp);
#pragma unroll
      for (int nt = 0; nt < 4; ++nt) Bf[nt] = frag(Bs, wc * 64 + nt * 16 + l15, kk * 4 + lgp);
#pragma unroll
      for (int mt = 0; mt < 4; ++mt)
#pragma unroll
        for (int nt = 0; nt < 4; ++nt) acc[mt][nt] = MFMA16(Af[mt], Bf[nt], acc[mt][nt]);
    }
    __syncthreads();
  }

  float bias[4]; int cg[4];
#pragma unroll
  for (int nt = 0; nt < 4; ++nt) {
    cg[nt] = n_t * 128 + wc * 64 + nt * 16 + l15;
    bias[nt] = proj_b[cg[nt]];
  }
#pragma unroll
  for (int mt = 0; mt < 4; ++mt) {
#pragma unroll
    for (int r = 0; r < 4; ++r) {
      size_t r_g = (size_t)(m_t * 128 + wr * 64 + mt * 16 + lgp * 4 + r);
#pragma unroll
      for (int nt = 0; nt < 4; ++nt)
        out[r_g * 256 + cg[nt]] = acc[mt][nt][r] + bias[nt];
    }
  }
}

extern "C" void kernel_launch(void* const* d_in, const int* in_sizes, int n_in,
                              void* d_out, int out_size, void* d_ws, size_t ws_size,
                              hipStream_t stream) {
  const float* x          = (const float*)d_in[0];
  const float* mask       = (const float*)d_in[1];
  const float* qkv_w      = (const float*)d_in[2];
  const float* qkv_b      = (const float*)d_in[3];
  const float* proj_w     = (const float*)d_in[4];
  const float* proj_b     = (const float*)d_in[5];
  const float* bias_table = (const float*)d_in[6];
  const int*   rel_index  = (const int*)d_in[7];

  char* ws = (char*)d_ws;
  float* cb      = (float*)(ws + CB_OFF);
  bf16*  qkv_wb  = (bf16*)(ws + QKVW_OFF);
  bf16*  proj_wb = (bf16*)(ws + PROJW_OFF);
  bf16*  qkv_i   = (bf16*)(ws + QI_OFF);     // q,k,v each TEN_ELEMS
  bf16*  ao      = (bf16*)(ws + AO_OFF);     // [200704][256]

  hipLaunchKernelGGL(build_cb_kernel, dim3(8192), dim3(256), 0, stream,
                     bias_table, mask, rel_index, cb);
  hipLaunchKernelGGL(cvt_w_kernel, dim3(1024), dim3(256), 0, stream,
                     qkv_w, proj_w, qkv_wb, proj_wb);
  hipLaunchKernelGGL(gemm_qkv_kernel, dim3(3136), dim3(512), 0, stream,
                     x, qkv_wb, qkv_b, qkv_i);
  hipLaunchKernelGGL(attn_kernel, dim3(8192), dim3(256), 0, stream,
                     qkv_i, cb, ao);
  hipLaunchKernelGGL(gemm_proj_kernel, dim3(3136), dim3(256), 0, stream,
                     ao, proj_wb, proj_b, (float*)d_out);
}

// Round 9
// 460.135 us; speedup vs baseline: 1.0324x; 1.0324x over previous
//
#include <hip/hip_runtime.h>
#include <hip/hip_bf16.h>

typedef __bf16 bf16;
typedef __bf16 bf16x8 __attribute__((ext_vector_type(8)));
typedef float  f32x4  __attribute__((ext_vector_type(4)));

#define MFMA16(A,B,C) __builtin_amdgcn_mfma_f32_16x16x32_bf16((A),(B),(C),0,0,0)

constexpr float SCALE = 0.17677669529663687f;   // 32^-0.5

// ---- ws layout (bytes) ----
constexpr size_t CB_OFF    = 0;                        // f32 [64 w][8 h][64 m][64 j] = 8 MB
constexpr size_t QKVW_OFF  = 8388608;                  // bf16 [768][256]
constexpr size_t PROJW_OFF = QKVW_OFF + 768*256*2;     // bf16 [256][256]
constexpr size_t QI_OFF    = PROJW_OFF + 256*256*2;    // 8,912,896 (256B aligned)
constexpr size_t TEN_ELEMS = 51380224ull;              // 4096*8*49*32 (bf16 elems)
constexpr size_t AO_OFF    = QI_OFF + 3*TEN_ELEMS*2;   // bf16 [200704][256]

__global__ __launch_bounds__(256) void build_cb_kernel(
    const float* __restrict__ bias_table, const float* __restrict__ mask,
    const int* __restrict__ rel_index, float* __restrict__ cb) {
  int idx = blockIdx.x * 256 + threadIdx.x;            // [64 w][8 h][64 m][64 j]
  int j = idx & 63, m = (idx >> 6) & 63, h = (idx >> 12) & 7, w = idx >> 15;
  float v = 0.f;
  if (j < 49 && m < 49)
    v = bias_table[rel_index[m * 49 + j] * 8 + h] + mask[(w * 49 + m) * 49 + j];
  cb[idx] = v;
}

__global__ __launch_bounds__(256) void cvt_w_kernel(
    const float* __restrict__ qkv_w, const float* __restrict__ proj_w,
    bf16* __restrict__ qkv_wb, bf16* __restrict__ proj_wb) {
  int i = blockIdx.x * 256 + threadIdx.x;              // 262,144 total
  if (i < 768 * 256) qkv_wb[i] = (bf16)qkv_w[i];
  else               proj_wb[i - 768 * 256] = (bf16)proj_w[i - 768 * 256];
}

// swizzled LDS tile helper: [row][64 k], 8-elem chunks XOR'd by row&7
__device__ __forceinline__ bf16x8 frag(const bf16* S, int row, int kchunk) {
  return *reinterpret_cast<const bf16x8*>(&S[row * 64 + ((kchunk ^ (row & 7)) * 8)]);
}

// ---------------------------------------------------------------------------
// GEMM A v3: R7's proven 128x128x64 tiling + T14 issue-early/write-late.
// qkv = x @ qkv_w^T (+bias, Q pre-scaled), scatter to q/k/v[b][h][49][32].
// grid 9408 = 8 XCD chunks x (196 m-tiles x 6 n-tiles), 256 thr / 4 waves.
// ---------------------------------------------------------------------------
__global__ __launch_bounds__(256) void gemm_qkv_kernel(
    const float* __restrict__ x, const bf16* __restrict__ qkv_wb,
    const float* __restrict__ qkv_b, bf16* __restrict__ qkv_i) {
  __shared__ __align__(16) bf16 As[128 * 64];
  __shared__ __align__(16) bf16 Bs[128 * 64];
  const int bid = blockIdx.x;
  const int xcd = bid & 7, idx = bid >> 3;             // 9408 = 8 * 1176
  const int m_t = xcd * 196 + idx / 6;
  const int n_t = idx % 6;
  const int tid = threadIdx.x;
  const int wv = tid >> 6, l = tid & 63, l15 = l & 15, lgp = l >> 4;
  const int wr = wv >> 1, wc = wv & 1;

  const f32x4 fzero = {0.f, 0.f, 0.f, 0.f};
  f32x4 acc[4][4];
#pragma unroll
  for (int mt = 0; mt < 4; ++mt)
#pragma unroll
    for (int nt = 0; nt < 4; ++nt) acc[mt][nt] = fzero;

  // per-thread staging coords: chunks c = i*256+tid -> row=c>>3, kc=c&7
  size_t a_off[4], b_off[4];
  int    l_off[4];
#pragma unroll
  for (int i = 0; i < 4; ++i) {
    int c = i * 256 + tid, row = c >> 3, kc = c & 7;
    a_off[i] = (size_t)(m_t * 128 + row) * 256 + kc * 8;
    b_off[i] = (size_t)(n_t * 128 + row) * 256 + kc * 8;
    l_off[i] = row * 64 + ((kc ^ (row & 7)) * 8);
  }

  f32x4  pa0[4], pa1[4];     // A prefetch (f32)
  bf16x8 pbv[4];             // B prefetch (bf16)

#define LOADK(K0)                                                        \
  {                                                                      \
    _Pragma("unroll")                                                    \
    for (int i = 0; i < 4; ++i) {                                        \
      pa0[i] = *reinterpret_cast<const f32x4*>(x + a_off[i] + (K0));     \
      pa1[i] = *reinterpret_cast<const f32x4*>(x + a_off[i] + (K0) + 4); \
      pbv[i] = *reinterpret_cast<const bf16x8*>(qkv_wb + b_off[i] + (K0)); \
    }                                                                    \
  }
#define STOREK()                                                         \
  {                                                                      \
    _Pragma("unroll")                                                    \
    for (int i = 0; i < 4; ++i) {                                        \
      bf16x8 v8;                                                         \
      _Pragma("unroll")                                                  \
      for (int e = 0; e < 4; ++e) {                                      \
        v8[e] = (bf16)pa0[i][e]; v8[e + 4] = (bf16)pa1[i][e];            \
      }                                                                  \
      *reinterpret_cast<bf16x8*>(&As[l_off[i]]) = v8;                    \
      *reinterpret_cast<bf16x8*>(&Bs[l_off[i]]) = pbv[i];                \
    }                                                                    \
  }

  LOADK(0);
  STOREK();
  __syncthreads();

#pragma unroll
  for (int ks = 0; ks < 4; ++ks) {
    if (ks < 3) LOADK((ks + 1) * 64);                  // T14: issue early
#pragma unroll
    for (int kk = 0; kk < 2; ++kk) {
      bf16x8 Af[4], Bf[4];
#pragma unroll
      for (int mt = 0; mt < 4; ++mt) Af[mt] = frag(As, wr * 64 + mt * 16 + l15, kk * 4 + lgp);
#pragma unroll
      for (int nt = 0; nt < 4; ++nt) Bf[nt] = frag(Bs, wc * 64 + nt * 16 + l15, kk * 4 + lgp);
#pragma unroll
      for (int mt = 0; mt < 4; ++mt)
#pragma unroll
        for (int nt = 0; nt < 4; ++nt) acc[mt][nt] = MFMA16(Af[mt], Bf[nt], acc[mt][nt]);
    }
    __syncthreads();                                   // LDS readers done
    if (ks < 3) {
      STOREK();                                        // write late
      __syncthreads();
    }
  }

  // epilogue: scatter to q/k/v [b][h][49][32] with bias (+SCALE for q)
  const int tsel = n_t >> 1;                           // 0:q 1:k 2:v (uniform)
  bf16* tb = qkv_i + (size_t)tsel * TEN_ELEMS;
  const float sc = (tsel == 0) ? SCALE : 1.0f;
  float bias[4]; int hh[4], dd[4];
#pragma unroll
  for (int nt = 0; nt < 4; ++nt) {
    int n_g = n_t * 128 + wc * 64 + nt * 16 + l15;
    bias[nt] = qkv_b[n_g];
    int nl = n_g & 255;
    hh[nt] = nl >> 5; dd[nt] = nl & 31;
  }
#pragma unroll
  for (int mt = 0; mt < 4; ++mt) {
#pragma unroll
    for (int r = 0; r < 4; ++r) {
      int r_g = m_t * 128 + wr * 64 + mt * 16 + lgp * 4 + r;
      int b = r_g / 49, m = r_g - b * 49;
#pragma unroll
      for (int nt = 0; nt < 4; ++nt) {
        tb[((size_t)(b * 8 + hh[nt]) * 49 + m) * 32 + dd[nt]] =
            (bf16)((acc[mt][nt][r] + bias[nt]) * sc);
      }
    }
  }
#undef LOADK
#undef STOREK
}

// ---------------------------------------------------------------------------
// D-frag pair (16x16 tiles Ta=rows 0-15, Tb=rows 16-31 along p) -> A/B frag
// over k=p. Validated R5/R6 audit. Output lane(l15,lgp) reg u: p = lgp*8+u.
// ---------------------------------------------------------------------------
__device__ __forceinline__ bf16x8 repack8(f32x4 Ta, f32x4 Tb, int l15, int lgp) {
  const int s0 = l15 + ((lgp & 1) << 5);
  const bool hi = (lgp & 2) != 0;
  bf16x8 F;
#pragma unroll
  for (int r = 0; r < 4; ++r) {
    float a0 = __shfl(Ta[r], s0);
    float b0 = __shfl(Tb[r], s0);
    F[r] = (bf16)(hi ? b0 : a0);
    float a1 = __shfl(Ta[r], s0 + 16);
    float b1 = __shfl(Tb[r], s0 + 16);
    F[r + 4] = (bf16)(hi ? b1 : a1);
  }
  return F;
}

// ---------------------------------------------------------------------------
// attn: one wave per (window b, head h). S^T = K.Q -> register softmax ->
// PV -> ao[b*49+m][256]. grid 8192 x 256 thr (4 waves).
// ---------------------------------------------------------------------------
__global__ __launch_bounds__(256) void attn_kernel(
    const bf16* __restrict__ qkv_i, const float* __restrict__ cb,
    bf16* __restrict__ ao) {
  __shared__ __align__(16) bf16 Vs[4][64 * 32];
  const int tid = threadIdx.x, wv = tid >> 6, l = tid & 63;
  const int l15 = l & 15, lgp = l >> 4;
  const int g = blockIdx.x * 4 + wv;
  const int b = g >> 3, h = g & 7;

  const bf16* qp = qkv_i + (size_t)(b * 8 + h) * 1568;          // 49*32
  const bf16* kp = qp + TEN_ELEMS;
  const bf16* vp = kp + TEN_ELEMS;
  bf16* vsm = &Vs[wv][0];

  // stage V rows 0..48: 1568 elems = 196 chunks of 8
#pragma unroll
  for (int i = 0; i < 4; ++i) {
    int c = i * 64 + l;
    if (c < 196)
      *reinterpret_cast<bf16x8*>(&vsm[c * 8]) =
          *reinterpret_cast<const bf16x8*>(vp + c * 8);
  }
  // zero rows 49..63: 480 elems = 60 chunks of 8
  {
    const bf16x8 z8 = {(bf16)0.f,(bf16)0.f,(bf16)0.f,(bf16)0.f,
                       (bf16)0.f,(bf16)0.f,(bf16)0.f,(bf16)0.f};
    if (l < 60) *reinterpret_cast<bf16x8*>(&vsm[1568 + l * 8]) = z8;
  }
  __syncthreads();

  bf16x8 Qf[4], Kf[4];
#pragma unroll
  for (int mt = 0; mt < 4; ++mt) {
    int m = mt * 16 + l15; int mc = m < 49 ? m : 48;
    Qf[mt] = *reinterpret_cast<const bf16x8*>(qp + mc * 32 + lgp * 8);
  }
#pragma unroll
  for (int jt = 0; jt < 4; ++jt) {
    int j = jt * 16 + l15; int jc = j < 49 ? j : 48;
    Kf[jt] = *reinterpret_cast<const bf16x8*>(kp + jc * 32 + lgp * 8);
  }
  // V B-frags: lane l15 = col d, k = j (per-elem LDS gather)
  bf16x8 Vb[2][2];
#pragma unroll
  for (int dt = 0; dt < 2; ++dt)
#pragma unroll
    for (int ksx = 0; ksx < 2; ++ksx) {
#pragma unroll
      for (int u = 0; u < 8; ++u) {
        int j = ksx * 32 + lgp * 8 + u;
        Vb[dt][ksx][u] = vsm[j * 32 + dt * 16 + l15];
      }
    }

  const float* cbp = cb + (size_t)((b & 63) * 8 + h) * 4096;
  bf16* aob = ao + (size_t)b * 12544;                  // 49*256
  const f32x4 fzero = {0.f, 0.f, 0.f, 0.f};

#pragma unroll
  for (int mt = 0; mt < 4; ++mt) {
    int mrow = mt * 16 + l15;
    f32x4 e4[4];
#pragma unroll
    for (int jt = 0; jt < 4; ++jt) e4[jt] = MFMA16(Kf[jt], Qf[mt], fzero);
#pragma unroll
    for (int jt = 0; jt < 4; ++jt) {
      f32x4 c4 = *reinterpret_cast<const f32x4*>(cbp + mrow * 64 + jt * 16 + lgp * 4);
#pragma unroll
      for (int r = 0; r < 4; ++r) e4[jt][r] += c4[r];
    }
    // kill pad keys j>=49 (jt==3: j = 48 + lgp*4 + r, keep only j==48)
    if (lgp != 0) { e4[3][0] = -3.0e38f; }
    e4[3][1] = -3.0e38f; e4[3][2] = -3.0e38f; e4[3][3] = -3.0e38f;

    float mx = e4[0][0];
#pragma unroll
    for (int jt = 0; jt < 4; ++jt)
#pragma unroll
      for (int r = 0; r < 4; ++r) mx = fmaxf(mx, e4[jt][r]);
    mx = fmaxf(mx, __shfl_xor(mx, 16));
    mx = fmaxf(mx, __shfl_xor(mx, 32));
    float sum = 0.f;
#pragma unroll
    for (int jt = 0; jt < 4; ++jt)
#pragma unroll
      for (int r = 0; r < 4; ++r) {
        float ex = __expf(e4[jt][r] - mx);
        e4[jt][r] = ex;
        sum += ex;
      }
    sum += __shfl_xor(sum, 16);
    sum += __shfl_xor(sum, 32);
    float rinv = 1.0f / sum;
#pragma unroll
    for (int jt = 0; jt < 4; ++jt)
#pragma unroll
      for (int r = 0; r < 4; ++r) e4[jt][r] *= rinv;   // normalized P

    bf16x8 Pf0 = repack8(e4[0], e4[1], l15, lgp);      // k = j in [0,32)
    bf16x8 Pf1 = repack8(e4[2], e4[3], l15, lgp);      // k = j in [32,64)
    f32x4 pv[2];
#pragma unroll
    for (int dt = 0; dt < 2; ++dt) {
      pv[dt] = MFMA16(Pf0, Vb[dt][0], fzero);
      pv[dt] = MFMA16(Pf1, Vb[dt][1], pv[dt]);
    }
    // D: col l15 = d, row = m = mt*16 + lgp*4 + r
#pragma unroll
    for (int r = 0; r < 4; ++r) {
      int m_g = mt * 16 + lgp * 4 + r;
      if (m_g < 49) {
#pragma unroll
        for (int dt = 0; dt < 2; ++dt)
          aob[m_g * 256 + h * 32 + dt * 16 + l15] = (bf16)pv[dt][r];
      }
    }
  }
}

// ---------------------------------------------------------------------------
// GEMM C: out = ao @ proj_w^T + proj_b  (dense f32 output)
// ---------------------------------------------------------------------------
__global__ __launch_bounds__(256) void gemm_proj_kernel(
    const bf16* __restrict__ ao, const bf16* __restrict__ proj_wb,
    const float* __restrict__ proj_b, float* __restrict__ out) {
  __shared__ __align__(16) bf16 As[128 * 64];
  __shared__ __align__(16) bf16 Bs[128 * 64];
  const int bid = blockIdx.x;                          // 3136 = 8 * 392
  const int xcd = bid & 7, idx = bid >> 3;
  const int m_t = xcd * 196 + idx / 2;
  const int n_t = idx % 2;
  const int tid = threadIdx.x;
  const int wv = tid >> 6, l = tid & 63, l15 = l & 15, lgp = l >> 4;
  const int wr = wv >> 1, wc = wv & 1;

  const f32x4 fzero = {0.f, 0.f, 0.f, 0.f};
  f32x4 acc[4][4];
#pragma unroll
  for (int mt = 0; mt < 4; ++mt)
#pragma unroll
    for (int nt = 0; nt < 4; ++nt) acc[mt][nt] = fzero;

  for (int ks = 0; ks < 4; ++ks) {
    const int k0 = ks * 64;
#pragma unroll
    for (int i = 0; i < 4; ++i) {
      int c = i * 256 + tid;
      int row = c >> 3, kc = c & 7;
      bf16x8 a8 = *reinterpret_cast<const bf16x8*>(
          ao + (size_t)(m_t * 128 + row) * 256 + k0 + kc * 8);
      *reinterpret_cast<bf16x8*>(&As[row * 64 + ((kc ^ (row & 7)) * 8)]) = a8;
      bf16x8 w8 = *reinterpret_cast<const bf16x8*>(
          proj_wb + (size_t)(n_t * 128 + row) * 256 + k0 + kc * 8);
      *reinterpret_cast<bf16x8*>(&Bs[row * 64 + ((kc ^ (row & 7)) * 8)]) = w8;
    }
    __syncthreads();
#pragma unroll
    for (int kk = 0; kk < 2; ++kk) {
      bf16x8 Af[4], Bf[4];
#pragma unroll
      for (int mt = 0; mt < 4; ++mt) Af[mt] = frag(As, wr * 64 + mt * 16 + l15, kk * 4 + lgp);
#pragma unroll
      for (int nt = 0; nt < 4; ++nt) Bf[nt] = frag(Bs, wc * 64 + nt * 16 + l15, kk * 4 + lgp);
#pragma unroll
      for (int mt = 0; mt < 4; ++mt)
#pragma unroll
        for (int nt = 0; nt < 4; ++nt) acc[mt][nt] = MFMA16(Af[mt], Bf[nt], acc[mt][nt]);
    }
    __syncthreads();
  }

  float bias[4]; int cg[4];
#pragma unroll
  for (int nt = 0; nt < 4; ++nt) {
    cg[nt] = n_t * 128 + wc * 64 + nt * 16 + l15;
    bias[nt] = proj_b[cg[nt]];
  }
#pragma unroll
  for (int mt = 0; mt < 4; ++mt) {
#pragma unroll
    for (int r = 0; r < 4; ++r) {
      size_t r_g = (size_t)(m_t * 128 + wr * 64 + mt * 16 + lgp * 4 + r);
#pragma unroll
      for (int nt = 0; nt < 4; ++nt)
        out[r_g * 256 + cg[nt]] = acc[mt][nt][r] + bias[nt];
    }
  }
}

extern "C" void kernel_launch(void* const* d_in, const int* in_sizes, int n_in,
                              void* d_out, int out_size, void* d_ws, size_t ws_size,
                              hipStream_t stream) {
  const float* x          = (const float*)d_in[0];
  const float* mask       = (const float*)d_in[1];
  const float* qkv_w      = (const float*)d_in[2];
  const float* qkv_b      = (const float*)d_in[3];
  const float* proj_w     = (const float*)d_in[4];
  const float* proj_b     = (const float*)d_in[5];
  const float* bias_table = (const float*)d_in[6];
  const int*   rel_index  = (const int*)d_in[7];

  char* ws = (char*)d_ws;
  float* cb      = (float*)(ws + CB_OFF);
  bf16*  qkv_wb  = (bf16*)(ws + QKVW_OFF);
  bf16*  proj_wb = (bf16*)(ws + PROJW_OFF);
  bf16*  qkv_i   = (bf16*)(ws + QI_OFF);     // q,k,v each TEN_ELEMS
  bf16*  ao      = (bf16*)(ws + AO_OFF);     // [200704][256]

  hipLaunchKernelGGL(build_cb_kernel, dim3(8192), dim3(256), 0, stream,
                     bias_table, mask, rel_index, cb);
  hipLaunchKernelGGL(cvt_w_kernel, dim3(1024), dim3(256), 0, stream,
                     qkv_w, proj_w, qkv_wb, proj_wb);
  hipLaunchKernelGGL(gemm_qkv_kernel, dim3(9408), dim3(256), 0, stream,
                     x, qkv_wb, qkv_b, qkv_i);
  hipLaunchKernelGGL(attn_kernel, dim3(8192), dim3(256), 0, stream,
                     qkv_i, cb, ao);
  hipLaunchKernelGGL(gemm_proj_kernel, dim3(3136), dim3(256), 0, stream,
                     ao, proj_wb, proj_b, (float*)d_out);
}

// Round 10
// 453.072 us; speedup vs baseline: 1.0485x; 1.0156x over previous
//
#include <hip/hip_runtime.h>
#include <hip/hip_bf16.h>

typedef __bf16 bf16;
typedef __bf16 bf16x8 __attribute__((ext_vector_type(8)));
typedef float  f32x4  __attribute__((ext_vector_type(4)));

#define MFMA16(A,B,C) __builtin_amdgcn_mfma_f32_16x16x32_bf16((A),(B),(C),0,0,0)

constexpr float SCALE = 0.17677669529663687f;   // 32^-0.5

// ---- ws layout (bytes) ----
constexpr size_t CB_OFF    = 0;                        // f32 [64 w][8 h][64 m][64 j] = 8 MB
constexpr size_t QKVW_OFF  = 8388608;                  // bf16 [768][256]
constexpr size_t PROJW_OFF = QKVW_OFF + 768*256*2;     // bf16 [256][256]
constexpr size_t QI_OFF    = PROJW_OFF + 256*256*2;    // 8,912,896 (256B aligned)
constexpr size_t TEN_ELEMS = 51380224ull;              // 4096*8*49*32 (bf16 elems)
constexpr size_t AO_OFF    = QI_OFF + 3*TEN_ELEMS*2;   // bf16 [200704][256]

__global__ __launch_bounds__(256) void build_cb_kernel(
    const float* __restrict__ bias_table, const float* __restrict__ mask,
    const int* __restrict__ rel_index, float* __restrict__ cb) {
  int idx = blockIdx.x * 256 + threadIdx.x;            // [64 w][8 h][64 m][64 j]
  int j = idx & 63, m = (idx >> 6) & 63, h = (idx >> 12) & 7, w = idx >> 15;
  float v = 0.f;
  if (j < 49 && m < 49)
    v = bias_table[rel_index[m * 49 + j] * 8 + h] + mask[(w * 49 + m) * 49 + j];
  cb[idx] = v;
}

__global__ __launch_bounds__(256) void cvt_w_kernel(
    const float* __restrict__ qkv_w, const float* __restrict__ proj_w,
    bf16* __restrict__ qkv_wb, bf16* __restrict__ proj_wb) {
  int i = blockIdx.x * 256 + threadIdx.x;              // 262,144 total
  if (i < 768 * 256) qkv_wb[i] = (bf16)qkv_w[i];
  else               proj_wb[i - 768 * 256] = (bf16)proj_w[i - 768 * 256];
}

// swizzled LDS tile helper: [row][64 k], 8-elem chunks XOR'd by row&7
__device__ __forceinline__ bf16x8 frag(const bf16* S, int row, int kchunk) {
  return *reinterpret_cast<const bf16x8*>(&S[row * 64 + ((kchunk ^ (row & 7)) * 8)]);
}

// ---------------------------------------------------------------------------
// GEMM A v4: qkv = x @ qkv_w^T (+bias, Q pre-scaled) -> q/k/v[b][h][49][32].
// BM=128, BN=256, BK=64 — x read 3x (not 6x): L3 traffic 1.8GB -> 0.75GB.
// 512 thr / 8 waves; wave (wr=wv>>2, wc=wv&3) owns a 64x64 quadrant.
// grid 4704 = 8 XCD chunks x (196 m x 3 n).
// ---------------------------------------------------------------------------
__global__ __launch_bounds__(512, 2) void gemm_qkv_kernel(
    const float* __restrict__ x, const bf16* __restrict__ qkv_wb,
    const float* __restrict__ qkv_b, bf16* __restrict__ qkv_i) {
  __shared__ __align__(16) bf16 As[128 * 64];
  __shared__ __align__(16) bf16 Bs[256 * 64];
  const int bid = blockIdx.x;
  const int xcd = bid & 7, idx = bid >> 3;             // 4704 = 8 * 588
  const int m_t = xcd * 196 + idx / 3;
  const int n_t = idx % 3;
  const int tid = threadIdx.x;
  const int wv = tid >> 6, l = tid & 63, l15 = l & 15, lgp = l >> 4;
  const int wr = wv >> 2, wc = wv & 3;

  const f32x4 fzero = {0.f, 0.f, 0.f, 0.f};
  f32x4 acc[4][4];
#pragma unroll
  for (int mt = 0; mt < 4; ++mt)
#pragma unroll
    for (int nt = 0; nt < 4; ++nt) acc[mt][nt] = fzero;

  for (int ks = 0; ks < 4; ++ks) {
    const int k0 = ks * 64;
    // stage A (f32 -> bf16): 1024 chunks of 8, 2 per thread
#pragma unroll
    for (int i = 0; i < 2; ++i) {
      int c = i * 512 + tid;
      int row = c >> 3, kc = c & 7;
      const float* src = x + (size_t)(m_t * 128 + row) * 256 + k0 + kc * 8;
      f32x4 f0 = *reinterpret_cast<const f32x4*>(src);
      f32x4 f1 = *reinterpret_cast<const f32x4*>(src + 4);
      bf16x8 v8;
#pragma unroll
      for (int e = 0; e < 4; ++e) { v8[e] = (bf16)f0[e]; v8[e + 4] = (bf16)f1[e]; }
      *reinterpret_cast<bf16x8*>(&As[row * 64 + ((kc ^ (row & 7)) * 8)]) = v8;
    }
    // stage B (bf16 weights): 2048 chunks of 8, 4 per thread
#pragma unroll
    for (int i = 0; i < 4; ++i) {
      int c = i * 512 + tid;
      int row = c >> 3, kc = c & 7;
      bf16x8 w8 = *reinterpret_cast<const bf16x8*>(
          qkv_wb + (size_t)(n_t * 256 + row) * 256 + k0 + kc * 8);
      *reinterpret_cast<bf16x8*>(&Bs[row * 64 + ((kc ^ (row & 7)) * 8)]) = w8;
    }
    __syncthreads();
#pragma unroll
    for (int kk = 0; kk < 2; ++kk) {
      bf16x8 Af[4], Bf[4];
#pragma unroll
      for (int mt = 0; mt < 4; ++mt) Af[mt] = frag(As, wr * 64 + mt * 16 + l15, kk * 4 + lgp);
#pragma unroll
      for (int nt = 0; nt < 4; ++nt) Bf[nt] = frag(Bs, wc * 64 + nt * 16 + l15, kk * 4 + lgp);
#pragma unroll
      for (int mt = 0; mt < 4; ++mt)
#pragma unroll
        for (int nt = 0; nt < 4; ++nt) acc[mt][nt] = MFMA16(Af[mt], Bf[nt], acc[mt][nt]);
    }
    __syncthreads();
  }

  // epilogue: scatter to q/k/v [b][h][49][32] with bias (+SCALE for q).
  // n-panels are 256-aligned so tsel = n_t (uniform per block).
  bf16* tb = qkv_i + (size_t)n_t * TEN_ELEMS;
  const float sc = (n_t == 0) ? SCALE : 1.0f;
  float bias[4]; int hh[4], dd[4];
#pragma unroll
  for (int nt = 0; nt < 4; ++nt) {
    int n_g = n_t * 256 + wc * 64 + nt * 16 + l15;
    bias[nt] = qkv_b[n_g];
    int nl = n_g & 255;
    hh[nt] = nl >> 5; dd[nt] = nl & 31;
  }
#pragma unroll
  for (int mt = 0; mt < 4; ++mt) {
#pragma unroll
    for (int r = 0; r < 4; ++r) {
      int r_g = m_t * 128 + wr * 64 + mt * 16 + lgp * 4 + r;
      int b = r_g / 49, m = r_g - b * 49;
#pragma unroll
      for (int nt = 0; nt < 4; ++nt) {
        tb[((size_t)(b * 8 + hh[nt]) * 49 + m) * 32 + dd[nt]] =
            (bf16)((acc[mt][nt][r] + bias[nt]) * sc);
      }
    }
  }
}

// ---------------------------------------------------------------------------
// D-frag pair (16x16 tiles Ta=rows 0-15, Tb=rows 16-31 along p) -> A/B frag
// over k=p. Validated R5/R6 audit. Output lane(l15,lgp) reg u: p = lgp*8+u.
// ---------------------------------------------------------------------------
__device__ __forceinline__ bf16x8 repack8(f32x4 Ta, f32x4 Tb, int l15, int lgp) {
  const int s0 = l15 + ((lgp & 1) << 5);
  const bool hi = (lgp & 2) != 0;
  bf16x8 F;
#pragma unroll
  for (int r = 0; r < 4; ++r) {
    float a0 = __shfl(Ta[r], s0);
    float b0 = __shfl(Tb[r], s0);
    F[r] = (bf16)(hi ? b0 : a0);
    float a1 = __shfl(Ta[r], s0 + 16);
    float b1 = __shfl(Tb[r], s0 + 16);
    F[r + 4] = (bf16)(hi ? b1 : a1);
  }
  return F;
}

// ---------------------------------------------------------------------------
// attn: one wave per (window b, head h). S^T = K.Q -> register softmax ->
// PV -> ao[b*49+m][256]. grid 8192 x 256 thr (4 waves).
// ---------------------------------------------------------------------------
__global__ __launch_bounds__(256) void attn_kernel(
    const bf16* __restrict__ qkv_i, const float* __restrict__ cb,
    bf16* __restrict__ ao) {
  __shared__ __align__(16) bf16 Vs[4][64 * 32];
  const int tid = threadIdx.x, wv = tid >> 6, l = tid & 63;
  const int l15 = l & 15, lgp = l >> 4;
  const int g = blockIdx.x * 4 + wv;
  const int b = g >> 3, h = g & 7;

  const bf16* qp = qkv_i + (size_t)(b * 8 + h) * 1568;          // 49*32
  const bf16* kp = qp + TEN_ELEMS;
  const bf16* vp = kp + TEN_ELEMS;
  bf16* vsm = &Vs[wv][0];

  // stage V rows 0..48: 1568 elems = 196 chunks of 8
#pragma unroll
  for (int i = 0; i < 4; ++i) {
    int c = i * 64 + l;
    if (c < 196)
      *reinterpret_cast<bf16x8*>(&vsm[c * 8]) =
          *reinterpret_cast<const bf16x8*>(vp + c * 8);
  }
  // zero rows 49..63: 480 elems = 60 chunks of 8
  {
    const bf16x8 z8 = {(bf16)0.f,(bf16)0.f,(bf16)0.f,(bf16)0.f,
                       (bf16)0.f,(bf16)0.f,(bf16)0.f,(bf16)0.f};
    if (l < 60) *reinterpret_cast<bf16x8*>(&vsm[1568 + l * 8]) = z8;
  }
  __syncthreads();

  bf16x8 Qf[4], Kf[4];
#pragma unroll
  for (int mt = 0; mt < 4; ++mt) {
    int m = mt * 16 + l15; int mc = m < 49 ? m : 48;
    Qf[mt] = *reinterpret_cast<const bf16x8*>(qp + mc * 32 + lgp * 8);
  }
#pragma unroll
  for (int jt = 0; jt < 4; ++jt) {
    int j = jt * 16 + l15; int jc = j < 49 ? j : 48;
    Kf[jt] = *reinterpret_cast<const bf16x8*>(kp + jc * 32 + lgp * 8);
  }
  // V B-frags: lane l15 = col d, k = j (per-elem LDS gather)
  bf16x8 Vb[2][2];
#pragma unroll
  for (int dt = 0; dt < 2; ++dt)
#pragma unroll
    for (int ksx = 0; ksx < 2; ++ksx) {
#pragma unroll
      for (int u = 0; u < 8; ++u) {
        int j = ksx * 32 + lgp * 8 + u;
        Vb[dt][ksx][u] = vsm[j * 32 + dt * 16 + l15];
      }
    }

  const float* cbp = cb + (size_t)((b & 63) * 8 + h) * 4096;
  bf16* aob = ao + (size_t)b * 12544;                  // 49*256
  const f32x4 fzero = {0.f, 0.f, 0.f, 0.f};

#pragma unroll
  for (int mt = 0; mt < 4; ++mt) {
    int mrow = mt * 16 + l15;
    f32x4 e4[4];
#pragma unroll
    for (int jt = 0; jt < 4; ++jt) e4[jt] = MFMA16(Kf[jt], Qf[mt], fzero);
#pragma unroll
    for (int jt = 0; jt < 4; ++jt) {
      f32x4 c4 = *reinterpret_cast<const f32x4*>(cbp + mrow * 64 + jt * 16 + lgp * 4);
#pragma unroll
      for (int r = 0; r < 4; ++r) e4[jt][r] += c4[r];
    }
    // kill pad keys j>=49 (jt==3: j = 48 + lgp*4 + r, keep only j==48)
    if (lgp != 0) { e4[3][0] = -3.0e38f; }
    e4[3][1] = -3.0e38f; e4[3][2] = -3.0e38f; e4[3][3] = -3.0e38f;

    float mx = e4[0][0];
#pragma unroll
    for (int jt = 0; jt < 4; ++jt)
#pragma unroll
      for (int r = 0; r < 4; ++r) mx = fmaxf(mx, e4[jt][r]);
    mx = fmaxf(mx, __shfl_xor(mx, 16));
    mx = fmaxf(mx, __shfl_xor(mx, 32));
    float sum = 0.f;
#pragma unroll
    for (int jt = 0; jt < 4; ++jt)
#pragma unroll
      for (int r = 0; r < 4; ++r) {
        float ex = __expf(e4[jt][r] - mx);
        e4[jt][r] = ex;
        sum += ex;
      }
    sum += __shfl_xor(sum, 16);
    sum += __shfl_xor(sum, 32);
    float rinv = 1.0f / sum;
#pragma unroll
    for (int jt = 0; jt < 4; ++jt)
#pragma unroll
      for (int r = 0; r < 4; ++r) e4[jt][r] *= rinv;   // normalized P

    bf16x8 Pf0 = repack8(e4[0], e4[1], l15, lgp);      // k = j in [0,32)
    bf16x8 Pf1 = repack8(e4[2], e4[3], l15, lgp);      // k = j in [32,64)
    f32x4 pv[2];
#pragma unroll
    for (int dt = 0; dt < 2; ++dt) {
      pv[dt] = MFMA16(Pf0, Vb[dt][0], fzero);
      pv[dt] = MFMA16(Pf1, Vb[dt][1], pv[dt]);
    }
    // D: col l15 = d, row = m = mt*16 + lgp*4 + r
#pragma unroll
    for (int r = 0; r < 4; ++r) {
      int m_g = mt * 16 + lgp * 4 + r;
      if (m_g < 49) {
#pragma unroll
        for (int dt = 0; dt < 2; ++dt)
          aob[m_g * 256 + h * 32 + dt * 16 + l15] = (bf16)pv[dt][r];
      }
    }
  }
}

// ---------------------------------------------------------------------------
// GEMM C v2: out = ao @ proj_w^T + proj_b. BM=128, BN=256 (full width):
// ao read ONCE. 512 thr / 8 waves. grid 1568 = 8 x 196.
// ---------------------------------------------------------------------------
__global__ __launch_bounds__(512, 2) void gemm_proj_kernel(
    const bf16* __restrict__ ao, const bf16* __restrict__ proj_wb,
    const float* __restrict__ proj_b, float* __restrict__ out) {
  __shared__ __align__(16) bf16 As[128 * 64];
  __shared__ __align__(16) bf16 Bs[256 * 64];
  const int bid = blockIdx.x;                          // 1568 = 8 * 196
  const int xcd = bid & 7, idx = bid >> 3;
  const int m_t = xcd * 196 + idx;
  const int tid = threadIdx.x;
  const int wv = tid >> 6, l = tid & 63, l15 = l & 15, lgp = l >> 4;
  const int wr = wv >> 2, wc = wv & 3;

  const f32x4 fzero = {0.f, 0.f, 0.f, 0.f};
  f32x4 acc[4][4];
#pragma unroll
  for (int mt = 0; mt < 4; ++mt)
#pragma unroll
    for (int nt = 0; nt < 4; ++nt) acc[mt][nt] = fzero;

  for (int ks = 0; ks < 4; ++ks) {
    const int k0 = ks * 64;
#pragma unroll
    for (int i = 0; i < 2; ++i) {
      int c = i * 512 + tid;
      int row = c >> 3, kc = c & 7;
      bf16x8 a8 = *reinterpret_cast<const bf16x8*>(
          ao + (size_t)(m_t * 128 + row) * 256 + k0 + kc * 8);
      *reinterpret_cast<bf16x8*>(&As[row * 64 + ((kc ^ (row & 7)) * 8)]) = a8;
    }
#pragma unroll
    for (int i = 0; i < 4; ++i) {
      int c = i * 512 + tid;
      int row = c >> 3, kc = c & 7;
      bf16x8 w8 = *reinterpret_cast<const bf16x8*>(
          proj_wb + (size_t)row * 256 + k0 + kc * 8);
      *reinterpret_cast<bf16x8*>(&Bs[row * 64 + ((kc ^ (row & 7)) * 8)]) = w8;
    }
    __syncthreads();
#pragma unroll
    for (int kk = 0; kk < 2; ++kk) {
      bf16x8 Af[4], Bf[4];
#pragma unroll
      for (int mt = 0; mt < 4; ++mt) Af[mt] = frag(As, wr * 64 + mt * 16 + l15, kk * 4 + lgp);
#pragma unroll
      for (int nt = 0; nt < 4; ++nt) Bf[nt] = frag(Bs, wc * 64 + nt * 16 + l15, kk * 4 + lgp);
#pragma unroll
      for (int mt = 0; mt < 4; ++mt)
#pragma unroll
        for (int nt = 0; nt < 4; ++nt) acc[mt][nt] = MFMA16(Af[mt], Bf[nt], acc[mt][nt]);
    }
    __syncthreads();
  }

  float bias[4]; int cg[4];
#pragma unroll
  for (int nt = 0; nt < 4; ++nt) {
    cg[nt] = wc * 64 + nt * 16 + l15;
    bias[nt] = proj_b[cg[nt]];
  }
#pragma unroll
  for (int mt = 0; mt < 4; ++mt) {
#pragma unroll
    for (int r = 0; r < 4; ++r) {
      size_t r_g = (size_t)(m_t * 128 + wr * 64 + mt * 16 + lgp * 4 + r);
#pragma unroll
      for (int nt = 0; nt < 4; ++nt)
        out[r_g * 256 + cg[nt]] = acc[mt][nt][r] + bias[nt];
    }
  }
}

extern "C" void kernel_launch(void* const* d_in, const int* in_sizes, int n_in,
                              void* d_out, int out_size, void* d_ws, size_t ws_size,
                              hipStream_t stream) {
  const float* x          = (const float*)d_in[0];
  const float* mask       = (const float*)d_in[1];
  const float* qkv_w      = (const float*)d_in[2];
  const float* qkv_b      = (const float*)d_in[3];
  const float* proj_w     = (const float*)d_in[4];
  const float* proj_b     = (const float*)d_in[5];
  const float* bias_table = (const float*)d_in[6];
  const int*   rel_index  = (const int*)d_in[7];

  char* ws = (char*)d_ws;
  float* cb      = (float*)(ws + CB_OFF);
  bf16*  qkv_wb  = (bf16*)(ws + QKVW_OFF);
  bf16*  proj_wb = (bf16*)(ws + PROJW_OFF);
  bf16*  qkv_i   = (bf16*)(ws + QI_OFF);     // q,k,v each TEN_ELEMS
  bf16*  ao      = (bf16*)(ws + AO_OFF);     // [200704][256]

  hipLaunchKernelGGL(build_cb_kernel, dim3(8192), dim3(256), 0, stream,
                     bias_table, mask, rel_index, cb);
  hipLaunchKernelGGL(cvt_w_kernel, dim3(1024), dim3(256), 0, stream,
                     qkv_w, proj_w, qkv_wb, proj_wb);
  hipLaunchKernelGGL(gemm_qkv_kernel, dim3(4704), dim3(512), 0, stream,
                     x, qkv_wb, qkv_b, qkv_i);
  hipLaunchKernelGGL(attn_kernel, dim3(8192), dim3(256), 0, stream,
                     qkv_i, cb, ao);
  hipLaunchKernelGGL(gemm_proj_kernel, dim3(1568), dim3(512), 0, stream,
                     ao, proj_wb, proj_b, (float*)d_out);
}